// Round 7
// baseline (191.547 us; speedup 1.0000x reference)
//
#include <hip/hip_runtime.h>

#define SBD   384
#define NCATS 64
#define EMB   48
#define HT    256
#define HC    128

typedef __attribute__((ext_vector_type(8))) short short8;
typedef __attribute__((ext_vector_type(4))) float f32x4;

__device__ __forceinline__ short f2bf(float x) {
    union { float f; unsigned u; } v; v.f = x;
    unsigned r = v.u + 0x7FFF + ((v.u >> 16) & 1);   // RNE
    return (short)(r >> 16);
}

__device__ __forceinline__ short8 cvt8(float4 a, float4 b) {
    short8 h;
    h[0] = f2bf(a.x); h[1] = f2bf(a.y); h[2] = f2bf(a.z); h[3] = f2bf(a.w);
    h[4] = f2bf(b.x); h[5] = f2bf(b.y); h[6] = f2bf(b.z); h[7] = f2bf(b.w);
    return h;
}

__device__ __forceinline__ void glds16(const void* g, void* l) {
    __builtin_amdgcn_global_load_lds((const __attribute__((address_space(1))) void*)g,
                                     (__attribute__((address_space(3))) void*)l, 16, 0, 0);
}

// ---------------------------------------------------------------------------
// Prep: weights -> bf16 images PRE-SWIZZLED in their LDS layout
// (byte ^= (n&7)<<4 within each [n][k] row-of-contiguous-k).
// iT1: 2 slices x [128n][384k] (96KB each). iBg: iT2 [48][256] @0,
// iC1 [128][64] @24576, iC2 [48][128] @40960 (52KB contiguous).
// ---------------------------------------------------------------------------
__global__ void prep_weights(const float* __restrict__ Wt1, const float* __restrict__ Wt2,
                             const float* __restrict__ Wc1, const float* __restrict__ Wc2,
                             char* __restrict__ iT1, char* __restrict__ iBg) {
    int t = blockIdx.x * blockDim.x + threadIdx.x;
    int stride = gridDim.x * blockDim.x;
    for (int g = t; g < 256 * 48; g += stride) {       // Wt1 [384k][256n]
        int n = g / 48, k0 = (g - n * 48) * 8;
        int s = n >> 7, nl = n & 127;
        short8 v;
        #pragma unroll
        for (int j = 0; j < 8; ++j) v[j] = f2bf(Wt1[(size_t)(k0 + j) * HT + n]);
        *(short8*)(iT1 + (size_t)s * 98304 + ((nl * 768 + k0 * 2) ^ ((nl & 7) << 4))) = v;
    }
    for (int g = t; g < 48 * 32; g += stride) {        // Wt2 [256k][48n]
        int n = g / 32, k0 = (g - n * 32) * 8;
        short8 v;
        #pragma unroll
        for (int j = 0; j < 8; ++j) v[j] = f2bf(Wt2[(size_t)(k0 + j) * EMB + n]);
        *(short8*)(iBg + ((n * 512 + k0 * 2) ^ ((n & 7) << 4))) = v;
    }
    for (int g = t; g < 128 * 8; g += stride) {        // Wc1 [64k][128n]
        int n = g / 8, k0 = (g - n * 8) * 8;
        short8 v;
        #pragma unroll
        for (int j = 0; j < 8; ++j) v[j] = f2bf(Wc1[(size_t)(k0 + j) * HC + n]);
        *(short8*)(iBg + 24576 + ((n * 128 + k0 * 2) ^ ((n & 7) << 4))) = v;
    }
    for (int g = t; g < 48 * 16; g += stride) {        // Wc2 [128k][48n]
        int n = g / 16, k0 = (g - n * 16) * 8;
        short8 v;
        #pragma unroll
        for (int j = 0; j < 8; ++j) v[j] = f2bf(Wc2[(size_t)(k0 + j) * EMB + n]);
        *(short8*)(iBg + 40960 + ((n * 256 + k0 * 2) ^ ((n & 7) << 4))) = v;
    }
}

// ---------------------------------------------------------------------------
// K1: H1t = relu(sbert @ Wt1 + bt1), bf16 [nbooks][256], plain layout.
// 256 persistent blocks (1/CU), 512 thr. Block = (n-slice of 128 cols) x
// (m-group of 16-book tiles, ~49 iterations). B-slice in LDS once (96KB glds).
// A: fp32 16-book tile via glds with pre-swizzled per-lane SOURCE (48KB dbuf).
// One __syncthreads per tile.
// ---------------------------------------------------------------------------
__global__ __launch_bounds__(512, 2) void k1_l1txt(
    const float* __restrict__ sbert, const char* __restrict__ iT1,
    const float* __restrict__ bt1, unsigned short* __restrict__ H1t, int nbooks)
{
    __shared__ char lds[147456];   // B 96K @0 ; A dbuf 2x24K @98304

    const int t  = threadIdx.x;
    const int w  = t >> 6;
    const int l  = t & 63;
    const int lr = l & 15;
    const int lg = l >> 4;
    const int ns = blockIdx.x & 1;
    const int mg = blockIdx.x >> 1;
    const int ntiles = nbooks >> 4;          // 6250 (nbooks % 16 == 0)

    // B-slice load (once): 6144 granules, 12 per thread
    const char* bsrc = iT1 + (size_t)ns * 98304;
    #pragma unroll
    for (int j = 0; j < 12; ++j)
        glds16(bsrc + j * 8192 + w * 1024 + l * 16, lds + j * 8192 + w * 1024 + l * 16);

    // A source-offset precompute (pre-swizzled): 3 granules/thread
    int asrc[3], aldo[3];
    #pragma unroll
    for (int j = 0; j < 3; ++j) {
        int g   = t + j * 512;
        int row = g / 96;                    // 96 granules per 1536B row
        int wb  = (g - row * 96) * 16;
        asrc[j] = row * 1536 + (wb ^ ((row & 7) << 4));
        aldo[j] = g * 16;
    }
    const char* sb = (const char*)sbert;

    // prologue: stage tile mg into buf0
    #pragma unroll
    for (int j = 0; j < 3; ++j)
        glds16(sb + (size_t)mg * 24576 + asrc[j], lds + 98304 + aldo[j]);

    const float bias = bt1[ns * 128 + w * 16 + lr];
    const int nl = w * 16 + lr;
    const int swz = (lr & 7) << 4;

    int i = 0;
    for (int m = mg; m < ntiles; m += 128, ++i) {
        const int cur = i & 1;
        __syncthreads();                      // stage(cur) complete, buf(cur^1) free
        const int mn = m + 128;
        if (mn < ntiles) {
            #pragma unroll
            for (int j = 0; j < 3; ++j)
                glds16(sb + (size_t)mn * 24576 + asrc[j],
                       lds + 98304 + (cur ^ 1) * 24576 + aldo[j]);
        }
        f32x4 acc = (f32x4){bias, bias, bias, bias};
        const char* ab = lds + 98304 + cur * 24576;
        #pragma unroll
        for (int ks = 0; ks < 12; ++ks) {
            float4 f0 = *(const float4*)(ab + ((lr * 1536 + ks * 128 + lg * 32) ^ swz));
            float4 f1 = *(const float4*)(ab + ((lr * 1536 + ks * 128 + lg * 32 + 16) ^ swz));
            short8 af = cvt8(f0, f1);
            short8 bf = *(const short8*)(lds + ((nl * 768 + ks * 64 + lg * 16) ^ swz));
            acc = __builtin_amdgcn_mfma_f32_16x16x32_bf16(af, bf, acc, 0, 0, 0);
        }
        #pragma unroll
        for (int r = 0; r < 4; ++r) {
            int row = m * 16 + lg * 4 + r;
            H1t[(size_t)row * 256 + ns * 128 + nl] =
                (unsigned short)f2bf(fmaxf(acc[r], 0.f));
        }
    }
}

// ---------------------------------------------------------------------------
// K2: fused tail. 256 persistent blocks, 256 thr (4 waves). Wave w owns rows
// 16w..16w+15 of each 64-book tile end-to-end -> NO barriers in the loop.
// LDS: Bgroup 52K @0 (once); H1t dbuf 2x32K @53248; H1c 16K @118784.
// H1t tiles glds'd per-wave (pre-swz source), counted vmcnt(8). mh via regs.
// ---------------------------------------------------------------------------
__global__ __launch_bounds__(256, 2) void k2_tail(
    const unsigned short* __restrict__ H1t, const float* __restrict__ mh,
    const char* __restrict__ iBg,
    const float* __restrict__ bt2, const float* __restrict__ bc1,
    const float* __restrict__ bc2, float* __restrict__ E, int nbooks)
{
    __shared__ char lds[135168];

    const int t  = threadIdx.x;
    const int w  = t >> 6;
    const int l  = t & 63;
    const int lr = l & 15;
    const int lg = l >> 4;
    const int ntiles = (nbooks + 63) >> 6;   // 1563
    const int swz = (lr & 7) << 4;

    // B-group (52KB) once: 13 granules/thread
    #pragma unroll
    for (int j = 0; j < 13; ++j)
        glds16(iBg + j * 4096 + t * 16, lds + j * 4096 + t * 16);

    // per-wave H1t source offsets (pre-swizzled), 8 glds/tile
    int hsrc[8];
    #pragma unroll
    for (int j = 0; j < 8; ++j) {
        int gt  = w * 512 + j * 64 + l;
        int row = gt >> 5;                   // 32 granules per 512B row
        int wb  = (gt & 31) * 16;
        hsrc[j] = row * 512 + (wb ^ ((row & 7) << 4));
    }
    const char* hb = (const char*)H1t;
    const int mrow = 16 * w + lr;

    int tile = blockIdx.x;
    // prologue: tile0 H1t + mh
    #pragma unroll
    for (int j = 0; j < 8; ++j)
        glds16(hb + (size_t)tile * 32768 + hsrc[j],
               lds + 53248 + w * 8192 + j * 1024 + l * 16);
    float4 mf0, mf1, mf2, mf3;
    {
        const float* mp = mh + (size_t)min(tile * 64 + mrow, nbooks - 1) * NCATS + lg * 8;
        mf0 = *(const float4*)(mp);      mf1 = *(const float4*)(mp + 4);
        mf2 = *(const float4*)(mp + 32); mf3 = *(const float4*)(mp + 36);
    }
    __syncthreads();                          // drains everything; Bgroup visible

    int i = 0;
    for (; tile < ntiles; tile += 256, ++i) {
        const int cur = i & 1;
        const int tn  = tile + 256;
        const bool has_next = tn < ntiles;
        if (has_next) {
            #pragma unroll
            for (int j = 0; j < 8; ++j)
                glds16(hb + (size_t)tn * 32768 + hsrc[j],
                       lds + 53248 + (cur ^ 1) * 32768 + w * 8192 + j * 1024 + l * 16);
            asm volatile("s_waitcnt vmcnt(8)" ::: "memory");
        } else {
            asm volatile("s_waitcnt vmcnt(0)" ::: "memory");
        }
        __builtin_amdgcn_sched_barrier(0);
        const char* hbuf = lds + 53248 + cur * 32768;

        // ---- L2 txt: rows 16w+lr, K=256 ----
        f32x4 acct[3];
        #pragma unroll
        for (int nt = 0; nt < 3; ++nt) { float b = bt2[nt * 16 + lr]; acct[nt] = (f32x4){b, b, b, b}; }
        #pragma unroll
        for (int ks = 0; ks < 8; ++ks) {
            short8 af = *(const short8*)(hbuf + ((mrow * 512 + (ks * 32 + lg * 8) * 2) ^ swz));
            #pragma unroll
            for (int nt = 0; nt < 3; ++nt) {
                short8 bf = *(const short8*)(lds + (((nt * 16 + lr) * 512 + (ks * 32 + lg * 8) * 2) ^ swz));
                acct[nt] = __builtin_amdgcn_mfma_f32_16x16x32_bf16(af, bf, acct[nt], 0, 0, 0);
            }
        }

        // ---- cat L1: mh regs @ Wc1, K=64 ----
        f32x4 accc[8];
        #pragma unroll
        for (int nt = 0; nt < 8; ++nt) { float b = bc1[nt * 16 + lr]; accc[nt] = (f32x4){b, b, b, b}; }
        {
            short8 af0 = cvt8(mf0, mf1);
            short8 af1 = cvt8(mf2, mf3);
            #pragma unroll
            for (int nt = 0; nt < 8; ++nt) {
                short8 b0 = *(const short8*)(lds + 24576 + (((nt * 16 + lr) * 128 + lg * 16) ^ swz));
                short8 b1 = *(const short8*)(lds + 24576 + (((nt * 16 + lr) * 128 + 64 + lg * 16) ^ swz));
                accc[nt] = __builtin_amdgcn_mfma_f32_16x16x32_bf16(af0, b0, accc[nt], 0, 0, 0);
                accc[nt] = __builtin_amdgcn_mfma_f32_16x16x32_bf16(af1, b1, accc[nt], 0, 0, 0);
            }
        }

        // ---- H1c (wave-private rows) ----
        #pragma unroll
        for (int nt = 0; nt < 8; ++nt)
            #pragma unroll
            for (int r = 0; r < 4; ++r) {
                int rr = 16 * w + lg * 4 + r;
                *(unsigned short*)(lds + 118784 + ((rr * 256 + (nt * 16 + lr) * 2) ^ ((rr & 7) << 4))) =
                    (unsigned short)f2bf(fmaxf(accc[nt][r], 0.f));
            }

        // issue next mh (regs free after cvt8 above)
        if (has_next) {
            const float* mp = mh + (size_t)min(tn * 64 + mrow, nbooks - 1) * NCATS + lg * 8;
            mf0 = *(const float4*)(mp);      mf1 = *(const float4*)(mp + 4);
            mf2 = *(const float4*)(mp + 32); mf3 = *(const float4*)(mp + 36);
        }

        asm volatile("s_waitcnt lgkmcnt(0)" ::: "memory");
        __builtin_amdgcn_sched_barrier(0);

        // ---- cat L2: H1c rows 16w+lr, K=128 ----
        f32x4 acc2[3];
        #pragma unroll
        for (int nt = 0; nt < 3; ++nt) { float b = bc2[nt * 16 + lr]; acc2[nt] = (f32x4){b, b, b, b}; }
        #pragma unroll
        for (int ks = 0; ks < 4; ++ks) {
            short8 af = *(const short8*)(lds + 118784 + ((mrow * 256 + (ks * 32 + lg * 8) * 2) ^ swz));
            #pragma unroll
            for (int nt = 0; nt < 3; ++nt) {
                short8 bf = *(const short8*)(lds + 40960 + (((nt * 16 + lr) * 256 + (ks * 32 + lg * 8) * 2) ^ swz));
                acc2[nt] = __builtin_amdgcn_mfma_f32_16x16x32_bf16(af, bf, acc2[nt], 0, 0, 0);
            }
        }

        // ---- combine, l2norm, store E ----
        f32x4 comb[3];
        #pragma unroll
        for (int nt = 0; nt < 3; ++nt)
            #pragma unroll
            for (int r = 0; r < 4; ++r) comb[nt][r] = 3.0f * acc2[nt][r] + acct[nt][r];
        #pragma unroll
        for (int r = 0; r < 4; ++r) {
            float ss = comb[0][r] * comb[0][r] + comb[1][r] * comb[1][r] + comb[2][r] * comb[2][r];
            ss += __shfl_xor(ss, 1); ss += __shfl_xor(ss, 2);
            ss += __shfl_xor(ss, 4); ss += __shfl_xor(ss, 8);
            float rn = rsqrtf(fmaxf(ss, 1e-12f));
            int grow = tile * 64 + 16 * w + lg * 4 + r;
            if (grow < nbooks) {
                #pragma unroll
                for (int nt = 0; nt < 3; ++nt)
                    E[(size_t)grow * EMB + nt * 16 + lr] = comb[nt][r] * rn;
            }
        }
    }
}

// ---------------------------------------------------------------------------
// Scoring: 16 lanes/sample, 3 dims/lane, shuffle-reduce.
// ---------------------------------------------------------------------------
__global__ __launch_bounds__(256) void score_kernel(
    const int* __restrict__ user_idx, const int* __restrict__ loc_idx,
    const int* __restrict__ pos_idx,  const int* __restrict__ neg_idx,
    const float* __restrict__ ucat, const float* __restrict__ utxt,
    const float* __restrict__ lcat, const float* __restrict__ ltxt,
    const float* __restrict__ E, float* __restrict__ out, int Bn)
{
    const int t    = threadIdx.x;
    const int lane = t & 15;
    const int s    = blockIdx.x * 16 + (t >> 4);
    if (s >= Bn) return;

    const int ui = user_idx[s];
    const int li = loc_idx[s];
    const int pi = pos_idx[s];
    const int ni = neg_idx[s];

    const int d0 = lane * 3;
    const float* uc = ucat + (size_t)ui * EMB + d0;
    const float* ut = utxt + (size_t)ui * EMB + d0;
    const float* lc = lcat + (size_t)li * EMB + d0;
    const float* lt = ltxt + (size_t)li * EMB + d0;
    const float* pp = E + (size_t)pi * EMB + d0;
    const float* nn = E + (size_t)ni * EMB + d0;

    float u0 = 3.0f * (uc[0] + lc[0]) + (ut[0] + lt[0]);
    float u1 = 3.0f * (uc[1] + lc[1]) + (ut[1] + lt[1]);
    float u2 = 3.0f * (uc[2] + lc[2]) + (ut[2] + lt[2]);

    float usq = u0 * u0 + u1 * u1 + u2 * u2;
    float ps  = u0 * pp[0] + u1 * pp[1] + u2 * pp[2];
    float ns  = u0 * nn[0] + u1 * nn[1] + u2 * nn[2];

    #pragma unroll
    for (int m = 1; m < 16; m <<= 1) {
        usq += __shfl_xor(usq, m);
        ps  += __shfl_xor(ps, m);
        ns  += __shfl_xor(ns, m);
    }

    if (lane == 0) {
        const float inv = rsqrtf(fmaxf(usq, 1e-12f)) * 20.0f;  // /TEMP
        out[2 * (size_t)s + 0] = ps * inv;
        out[2 * (size_t)s + 1] = ns * inv;
    }
}

extern "C" void kernel_launch(void* const* d_in, const int* in_sizes, int n_in,
                              void* d_out, int out_size, void* d_ws, size_t ws_size,
                              hipStream_t stream) {
    const int*   user_idx = (const int*)d_in[0];
    const int*   loc_idx  = (const int*)d_in[1];
    const int*   pos_idx  = (const int*)d_in[2];
    const int*   neg_idx  = (const int*)d_in[3];
    const float* ucat     = (const float*)d_in[4];
    const float* utxt     = (const float*)d_in[5];
    const float* lcat     = (const float*)d_in[6];
    const float* ltxt     = (const float*)d_in[7];
    const float* sbert    = (const float*)d_in[8];
    const float* mh       = (const float*)d_in[9];
    const float* Wc1      = (const float*)d_in[10];
    const float* bc1      = (const float*)d_in[11];
    const float* Wc2      = (const float*)d_in[12];
    const float* bc2      = (const float*)d_in[13];
    const float* Wt1      = (const float*)d_in[14];
    const float* bt1      = (const float*)d_in[15];
    const float* Wt2      = (const float*)d_in[16];
    const float* bt2      = (const float*)d_in[17];

    const int Bn     = in_sizes[0];
    const int nbooks = in_sizes[8] / SBD;          // 100000
    const int ntiles2 = (nbooks + 63) / 64;

    char* ws = (char*)d_ws;
    float* E = (float*)ws;
    size_t off = ((size_t)nbooks * EMB * 4 + 255) & ~(size_t)255;
    char* iT1 = ws + off;  off += 196608;
    char* iBg = ws + off;  off += 53248;
    off = (off + 511) & ~(size_t)511;
    unsigned short* H1t = (unsigned short*)(ws + off);   // ntiles2*64 rows x 512B

    hipLaunchKernelGGL(prep_weights, dim3(64), dim3(256), 0, stream,
                       Wt1, Wt2, Wc1, Wc2, iT1, iBg);

    hipLaunchKernelGGL(k1_l1txt, dim3(256), dim3(512), 0, stream,
                       sbert, iT1, bt1, H1t, nbooks);

    hipLaunchKernelGGL(k2_tail, dim3(256), dim3(256), 0, stream,
                       H1t, mh, iBg, bt2, bc1, bc2, E, nbooks);

    const int nblocksB = (Bn + 15) / 16;
    hipLaunchKernelGGL(score_kernel, dim3(nblocksB), dim3(256), 0, stream,
                       user_idx, loc_idx, pos_idx, neg_idx,
                       ucat, utxt, lcat, ltxt, E, (float*)d_out, Bn);
    (void)ntiles2; (void)ws_size; (void)out_size; (void)n_in;
}